// Round 3
// baseline (473.366 us; speedup 1.0000x reference)
//
#include <hip/hip_runtime.h>
#include <hip/hip_bf16.h>
#include <stdint.h>

#define HH 96
#define WW 96
#define NCH 256
#define PH 95
#define PW 95
#define NP 9025          // PH*PW
#define NTILE 71
#define NPAD 9088        // NTILE*128
#define DD 1024          // 4*NCH
#define FEPS 1e-8f
#define NBLK 5041        // NTILE*NTILE

typedef __attribute__((ext_vector_type(8))) short bf16x8;
typedef __attribute__((ext_vector_type(4))) float f32x4;
typedef unsigned long long u64;
typedef unsigned int u32;
using bf16 = __hip_bfloat16;

// monotone float key + inverted index => u64 max == (max score, smallest idx)
__device__ __forceinline__ u64 packSI(float v, u32 idx) {
  u32 b = __float_as_uint(v);
  u32 key = (b & 0x80000000u) ? ~b : (b | 0x80000000u);
  return ((u64)key << 32) | (u64)(~idx);
}

__global__ __launch_bounds__(256) void k_init(u64* rowP, u64* colP, bf16* Sn, bf16* Tn,
                                              float* sq_s, float* sq_t) {
  int i = blockIdx.x * 256 + threadIdx.x;
  if (i < NPAD) { rowP[i] = 0ull; colP[i] = 0ull; }
  if (i >= NP && i < NPAD) { sq_s[i] = 0.f; sq_t[i] = 0.f; }
  const int padWords = (NPAD - NP) * DD / 2;  // u32 words in pad rows
  u32* ps = (u32*)(Sn + (size_t)NP * DD);
  u32* pt = (u32*)(Tn + (size_t)NP * DD);
  for (int j = i; j < padWords; j += gridDim.x * 256) { ps[j] = 0u; pt[j] = 0u; }
}

// per-pixel channel sum of squares
__global__ __launch_bounds__(256) void k_q(const float* __restrict__ src,
                                           const float* __restrict__ tgt,
                                           float* __restrict__ q_s,
                                           float* __restrict__ q_t) {
  int p = blockIdx.x * 256 + threadIdx.x;  // 36*256 == 9216 exactly
  const float* img = blockIdx.y ? tgt : src;
  float acc = 0.f;
  #pragma unroll 8
  for (int c = 0; c < NCH; ++c) {
    float v = img[(size_t)c * (HH * WW) + p];
    acc = fmaf(v, v, acc);
  }
  (blockIdx.y ? q_t : q_s)[p] = acc;
}

// per-patch squared norm = 4-point sum of q
__global__ __launch_bounds__(256) void k_sq(const float* __restrict__ q_s,
                                            const float* __restrict__ q_t,
                                            float* __restrict__ sq_s,
                                            float* __restrict__ sq_t) {
  int n = blockIdx.x * 256 + threadIdx.x;
  if (n >= NP) return;
  int y = n / PW, x = n - y * PW;
  int b = y * WW + x;
  sq_s[n] = q_s[b] + q_s[b + 1] + q_s[b + WW] + q_s[b + WW + 1];
  sq_t[n] = q_t[b] + q_t[b + 1] + q_t[b + WW] + q_t[b + WW + 1];
}

// normalized bf16 patch matrix [NPAD][DD], written via LDS transpose
__global__ __launch_bounds__(128) void k_norm(const float* __restrict__ img,
                                              const float* __restrict__ sq,
                                              bf16* __restrict__ out) {
  __shared__ float tile[64 * 129];
  __shared__ float rn[PW];
  int y = blockIdx.y;
  int d0 = blockIdx.x * 64;     // 16 chunks of 64 d's
  int k = d0 >> 8;              // which 2x2 shift
  int c0 = d0 & 255;
  int iy = k >> 1, jx = k & 1;
  int t = threadIdx.x;
  if (t < PW) rn[t] = 1.f / (sqrtf(sq[y * PW + t]) + FEPS);
  int x = t;
  const float* base = img + (size_t)(y + iy) * WW + jx;
  #pragma unroll 4
  for (int dl = 0; dl < 64; ++dl) {
    int c = c0 + dl;
    float v = (x < PW) ? base[(size_t)c * (HH * WW) + x] : 0.f;
    tile[dl * 129 + x] = v;
  }
  __syncthreads();
  int dl = t & 63, xh = t >> 6;
  for (int xl = xh; xl < PW; xl += 2) {
    out[(size_t)(y * PW + xl) * DD + d0 + dl] =
        __float2bfloat16(tile[dl * 129 + xl] * rn[xl]);
  }
}

// 128x128-tile bf16 MFMA GEMM (scores = Tn * Sn^T) with fused bidirectional argmax
__global__ __launch_bounds__(256) void k_gemm(const bf16* __restrict__ Tn,
                                              const bf16* __restrict__ Sn,
                                              u64* __restrict__ rowP,
                                              u64* __restrict__ colP) {
  __shared__ __align__(16) bf16 As[128 * 32];
  __shared__ __align__(16) bf16 Bs[128 * 32];

  int bid = blockIdx.x;
  // bijective XCD swizzle (m204): NBLK % 8 == 1
  const int q = NBLK / 8, r = NBLK % 8;
  int xcd = bid & 7, idx = bid >> 3;
  int swz = (xcd < r) ? (xcd * (q + 1) + idx) : (r * (q + 1) + (xcd - r) * q + idx);
  int tileR = (swz / NTILE) * 128;   // target rows
  int tileC = (swz % NTILE) * 128;   // source cols

  int tid = threadIdx.x;
  int lane = tid & 63;
  int wid = tid >> 6;
  int wr = (wid >> 1) * 64, wc = (wid & 1) * 64;
  int lcol = lane & 15, lrow = lane >> 4;

  f32x4 acc[4][4] = {};

  for (int kt = 0; kt < DD / 32; ++kt) {
    int k0 = kt * 32;
    __syncthreads();
    #pragma unroll
    for (int i = 0; i < 2; ++i) {
      int ofs = (i * 256 + tid) * 16;     // byte offset in 8KB tile
      int row = ofs >> 6;                 // 64B per row of 32 bf16
      int col = (ofs & 63) >> 1;          // element within row
      const bf16* ga = Tn + (size_t)(tileR + row) * DD + k0 + col;
      const bf16* gb = Sn + (size_t)(tileC + row) * DD + k0 + col;
      __builtin_amdgcn_global_load_lds(
          (const __attribute__((address_space(1))) void*)ga,
          (__attribute__((address_space(3))) void*)((char*)As + ofs), 16, 0, 0);
      __builtin_amdgcn_global_load_lds(
          (const __attribute__((address_space(1))) void*)gb,
          (__attribute__((address_space(3))) void*)((char*)Bs + ofs), 16, 0, 0);
    }
    __syncthreads();
    bf16x8 af[4], bfr[4];
    int kk = lrow * 8;
    #pragma unroll
    for (int m = 0; m < 4; ++m)
      af[m] = *(const bf16x8*)(As + (wr + m * 16 + lcol) * 32 + kk);
    #pragma unroll
    for (int n = 0; n < 4; ++n)
      bfr[n] = *(const bf16x8*)(Bs + (wc + n * 16 + lcol) * 32 + kk);
    #pragma unroll
    for (int m = 0; m < 4; ++m)
      #pragma unroll
      for (int n = 0; n < 4; ++n)
        acc[m][n] = __builtin_amdgcn_mfma_f32_16x16x32_bf16(af[m], bfr[n], acc[m][n], 0, 0, 0);
  }

  // ---- row argmax (per target row, over this tile's 128 source cols)
  #pragma unroll
  for (int m = 0; m < 4; ++m) {
    #pragma unroll
    for (int j = 0; j < 4; ++j) {
      u64 best = 0ull;
      #pragma unroll
      for (int n = 0; n < 4; ++n) {
        u32 cidx = (u32)(tileC + wc + n * 16 + lcol);
        u64 p = packSI(acc[m][n][j], cidx);
        best = p > best ? p : best;
      }
      #pragma unroll
      for (int s = 1; s < 16; s <<= 1) {
        u64 o = __shfl_xor(best, s, 64);
        best = o > best ? o : best;
      }
      if (lcol == 0)
        atomicMax(&rowP[tileR + wr + m * 16 + lrow * 4 + j], best);
    }
  }
  // ---- col argmax (per source col, over this tile's 128 target rows)
  #pragma unroll
  for (int n = 0; n < 4; ++n) {
    u64 best = 0ull;
    #pragma unroll
    for (int m = 0; m < 4; ++m)
      #pragma unroll
      for (int j = 0; j < 4; ++j) {
        u32 ridx = (u32)(tileR + wr + m * 16 + lrow * 4 + j);
        u64 p = packSI(acc[m][n][j], ridx);
        best = p > best ? p : best;
      }
    #pragma unroll
    for (int s = 16; s < 64; s <<= 1) {
      u64 o = __shfl_xor(best, s, 64);
      best = o > best ? o : best;
    }
    if (lrow == 0)
      atomicMax(&colP[tileC + wc + n * 16 + lcol], best);
  }
}

// final losses from packed (score, idx) + squared norms; single block, deterministic
__global__ __launch_bounds__(1024) void k_loss(const u64* __restrict__ rowP,
                                               const u64* __restrict__ colP,
                                               const float* __restrict__ sq_s,
                                               const float* __restrict__ sq_t,
                                               float* __restrict__ out) {
  __shared__ float r0[1024], r1[1024];
  int t = threadIdx.x;
  float lt = 0.f, ls = 0.f;
  for (int n = t; n < NP; n += 1024) {
    {
      u64 p = rowP[n];
      u32 key = (u32)(p >> 32);
      u32 b = (key & 0x80000000u) ? (key ^ 0x80000000u) : ~key;
      float sc = __uint_as_float(b);
      u32 m = ~((u32)p);
      float a = sq_t[n], c = sq_s[m];
      lt += a + c - 2.f * sc * (sqrtf(a) + FEPS) * (sqrtf(c) + FEPS);
    }
    {
      u64 p = colP[n];
      u32 key = (u32)(p >> 32);
      u32 b = (key & 0x80000000u) ? (key ^ 0x80000000u) : ~key;
      float sc = __uint_as_float(b);
      u32 m = ~((u32)p);
      float a = sq_s[n], c = sq_t[m];
      ls += a + c - 2.f * sc * (sqrtf(a) + FEPS) * (sqrtf(c) + FEPS);
    }
  }
  r0[t] = lt; r1[t] = ls;
  __syncthreads();
  for (int s = 512; s > 0; s >>= 1) {
    if (t < s) { r0[t] += r0[t + s]; r1[t] += r1[t + s]; }
    __syncthreads();
  }
  if (t == 0) {
    const float scale = 0.5f / ((float)NP * (float)DD);
    out[0] = r0[0] * scale;   // loss_target
    out[1] = r1[0] * scale;   // loss_source
  }
}

extern "C" void kernel_launch(void* const* d_in, const int* in_sizes, int n_in,
                              void* d_out, int out_size, void* d_ws, size_t ws_size,
                              hipStream_t stream) {
  const float* src = (const float*)d_in[0];
  const float* tgt = (const float*)d_in[1];
  float* out = (float*)d_out;
  char* ws = (char*)d_ws;
  size_t o = 0;
  bf16* Sn = (bf16*)(ws + o); o += (size_t)NPAD * DD * 2;
  bf16* Tn = (bf16*)(ws + o); o += (size_t)NPAD * DD * 2;
  float* sq_s = (float*)(ws + o); o += (size_t)NPAD * 4;
  float* sq_t = (float*)(ws + o); o += (size_t)NPAD * 4;
  float* q_s = (float*)(ws + o); o += (size_t)HH * WW * 4;
  float* q_t = (float*)(ws + o); o += (size_t)HH * WW * 4;
  u64* rowP = (u64*)(ws + o); o += (size_t)NPAD * 8;
  u64* colP = (u64*)(ws + o); o += (size_t)NPAD * 8;
  if (ws_size < o) return;  // ~35.8 MiB needed

  k_init<<<36, 256, 0, stream>>>(rowP, colP, Sn, Tn, sq_s, sq_t);
  k_q<<<dim3(36, 2), 256, 0, stream>>>(src, tgt, q_s, q_t);
  k_sq<<<36, 256, 0, stream>>>(q_s, q_t, sq_s, sq_t);
  k_norm<<<dim3(16, PH), 128, 0, stream>>>(src, sq_s, Sn);
  k_norm<<<dim3(16, PH), 128, 0, stream>>>(tgt, sq_t, Tn);
  k_gemm<<<NBLK, 256, 0, stream>>>(Tn, Sn, rowP, colP);
  k_loss<<<1, 1024, 0, stream>>>(rowP, colP, sq_s, sq_t, out);
}

// Round 4
// 402.806 us; speedup vs baseline: 1.1752x; 1.1752x over previous
//
#include <hip/hip_runtime.h>
#include <hip/hip_bf16.h>
#include <stdint.h>

#define HH 96
#define WW 96
#define NCH 256
#define PH 95
#define PW 95
#define NP 9025          // PH*PW
#define DD 1024          // 4*NCH
#define FEPS 1e-8f

#define BM 256           // tile M=N
#define BK 64            // K-step
#define NT2 36           // tiles per dim
#define NPAD2 9216       // NT2*BM
#define NBLK2 1296       // NT2*NT2 (divisible by 8)
#define KT 16            // DD/BK

typedef __attribute__((ext_vector_type(8))) short bf16x8;
typedef __attribute__((ext_vector_type(4))) float f32x4;
typedef unsigned long long u64;
typedef unsigned int u32;
using bf16 = __hip_bfloat16;

// monotone float key + inverted index => u64 max == (max score, smallest idx)
__device__ __forceinline__ u64 packSI(float v, u32 idx) {
  u32 b = __float_as_uint(v);
  u32 key = (b & 0x80000000u) ? ~b : (b | 0x80000000u);
  return ((u64)key << 32) | (u64)(~idx);
}
__device__ __forceinline__ u64 umax(u64 a, u64 b) { return a > b ? a : b; }

// zero pad rows NP..NPAD2 of Sn,Tn (so pad scores are exactly 0 and never win)
__global__ __launch_bounds__(256) void k_init(bf16* Sn, bf16* Tn) {
  int i = blockIdx.x * 256 + threadIdx.x;
  const int padWords = (NPAD2 - NP) * DD / 2;  // u32 words
  u32* ps = (u32*)(Sn + (size_t)NP * DD);
  u32* pt = (u32*)(Tn + (size_t)NP * DD);
  for (int j = i; j < padWords; j += gridDim.x * 256) { ps[j] = 0u; pt[j] = 0u; }
}

// per-pixel channel sum of squares
__global__ __launch_bounds__(256) void k_q(const float* __restrict__ src,
                                           const float* __restrict__ tgt,
                                           float* __restrict__ q_s,
                                           float* __restrict__ q_t) {
  int p = blockIdx.x * 256 + threadIdx.x;  // 36*256 == 9216 exactly
  const float* img = blockIdx.y ? tgt : src;
  float acc = 0.f;
  #pragma unroll 8
  for (int c = 0; c < NCH; ++c) {
    float v = img[(size_t)c * (HH * WW) + p];
    acc = fmaf(v, v, acc);
  }
  (blockIdx.y ? q_t : q_s)[p] = acc;
}

// per-patch squared norm = 4-point sum of q
__global__ __launch_bounds__(256) void k_sq(const float* __restrict__ q_s,
                                            const float* __restrict__ q_t,
                                            float* __restrict__ sq_s,
                                            float* __restrict__ sq_t) {
  int n = blockIdx.x * 256 + threadIdx.x;
  if (n >= NP) return;
  int y = n / PW, x = n - y * PW;
  int b = y * WW + x;
  sq_s[n] = q_s[b] + q_s[b + 1] + q_s[b + WW] + q_s[b + WW + 1];
  sq_t[n] = q_t[b] + q_t[b + 1] + q_t[b + WW] + q_t[b + WW + 1];
}

// normalized bf16 patch matrix [NPAD2][DD], written via LDS transpose
__global__ __launch_bounds__(128) void k_norm(const float* __restrict__ img,
                                              const float* __restrict__ sq,
                                              bf16* __restrict__ out) {
  __shared__ float tile[64 * 129];
  __shared__ float rn[PW];
  int y = blockIdx.y;
  int d0 = blockIdx.x * 64;     // 16 chunks of 64 d's
  int k = d0 >> 8;              // which 2x2 shift
  int c0 = d0 & 255;
  int iy = k >> 1, jx = k & 1;
  int t = threadIdx.x;
  if (t < PW) rn[t] = 1.f / (sqrtf(sq[y * PW + t]) + FEPS);
  int x = t;
  const float* base = img + (size_t)(y + iy) * WW + jx;
  #pragma unroll 4
  for (int dl = 0; dl < 64; ++dl) {
    int c = c0 + dl;
    float v = (x < PW) ? base[(size_t)c * (HH * WW) + x] : 0.f;
    tile[dl * 129 + x] = v;
  }
  __syncthreads();
  int dl = t & 63, xh = t >> 6;
  for (int xl = xh; xl < PW; xl += 2) {
    out[(size_t)(y * PW + xl) * DD + d0 + dl] =
        __float2bfloat16(tile[dl * 129 + xl] * rn[xl]);
  }
}

// 256x256-tile bf16 MFMA GEMM (scores = Tn * Sn^T), counted-vmcnt 2-phase
// pipeline, fused bidirectional argmax -> per-tile partials (no atomics).
__global__ __launch_bounds__(512, 2) void k_gemm(const bf16* __restrict__ Tn,
                                                 const bf16* __restrict__ Sn,
                                                 u64* __restrict__ rowPart,
                                                 u64* __restrict__ colPart) {
  __shared__ __align__(16) char lds[4 * BM * BK * 2];  // 128 KiB: A0 B0 A1 B1
  bf16* A0 = (bf16*)lds;
  bf16* B0 = A0 + BM * BK;
  bf16* A1 = B0 + BM * BK;
  bf16* B1 = A1 + BM * BK;

  int bid = blockIdx.x;
  // XCD swizzle: NBLK2 % 8 == 0 -> simple chunked form
  int swz = (bid & 7) * (NBLK2 / 8) + (bid >> 3);
  int rt = swz / NT2, ct = swz % NT2;
  int tileR = rt * BM, tileC = ct * BM;

  int tid = threadIdx.x;
  int lane = tid & 63, wid = tid >> 6;
  int wm = wid >> 2, wn = wid & 3;       // 2 x 4 wave grid; per-wave out 128x64
  int lcol = lane & 15, lrow = lane >> 4;

  const bf16* gA = Tn + (size_t)tileR * DD;
  const bf16* gB = Sn + (size_t)tileC * DD;

  f32x4 acc[8][4] = {};

  auto STAGE = [&](bf16* dA, bf16* dB, int kt) {
    int k0 = kt * BK;
    #pragma unroll
    for (int p = 0; p < 4; ++p) {
      int ofs = (p * 512 + tid) * 16;     // byte offset in 32KB tile
      int row = ofs >> 7;                 // 128B per row of 64 bf16
      int col = (ofs & 127) >> 1;
      __builtin_amdgcn_global_load_lds(
          (const __attribute__((address_space(1))) void*)(gA + (size_t)row * DD + k0 + col),
          (__attribute__((address_space(3))) void*)((char*)dA + ofs), 16, 0, 0);
      __builtin_amdgcn_global_load_lds(
          (const __attribute__((address_space(1))) void*)(gB + (size_t)row * DD + k0 + col),
          (__attribute__((address_space(3))) void*)((char*)dB + ofs), 16, 0, 0);
    }
  };

  bf16 *cA = A0, *cB = B0, *nA = A1, *nB = B1;
  STAGE(cA, cB, 0);

  for (int t = 0; t < KT; ++t) {
    if (t + 1 < KT) {
      STAGE(nA, nB, t + 1);   // prefetch next K-tile into other buffer
      // wait only for tile t's 8 loads; keep the 8 prefetch loads in flight
      asm volatile("s_waitcnt vmcnt(8)" ::: "memory");
    } else {
      asm volatile("s_waitcnt vmcnt(0)" ::: "memory");
    }
    __builtin_amdgcn_s_barrier();

    const bf16* aw = cA + (wm * 128 + lcol) * BK + lrow * 8;
    const bf16* bw = cB + (wn * 64 + lcol) * BK + lrow * 8;
    #pragma unroll
    for (int ks = 0; ks < 2; ++ks) {
      bf16x8 bf_[4];
      #pragma unroll
      for (int n = 0; n < 4; ++n)
        bf_[n] = *(const bf16x8*)(bw + n * 16 * BK + ks * 32);
      #pragma unroll
      for (int mh = 0; mh < 2; ++mh) {
        bf16x8 af[4];
        #pragma unroll
        for (int m4 = 0; m4 < 4; ++m4)
          af[m4] = *(const bf16x8*)(aw + (mh * 4 + m4) * 16 * BK + ks * 32);
        #pragma unroll
        for (int m4 = 0; m4 < 4; ++m4)
          #pragma unroll
          for (int n = 0; n < 4; ++n)
            acc[mh * 4 + m4][n] =
                __builtin_amdgcn_mfma_f32_16x16x32_bf16(af[m4], bf_[n], acc[mh * 4 + m4][n], 0, 0, 0);
      }
    }
    __builtin_amdgcn_s_barrier();   // all waves done reading before re-staging
    bf16* s;
    s = cA; cA = nA; nA = s;
    s = cB; cB = nB; nB = s;
  }

  // ---- epilogue: bidirectional argmax to per-tile partials, no atomics ----
  __syncthreads();                  // full drain; LDS now reusable
  u64* rowLds = (u64*)lds;          // [4 wn][256 rows]  8KB
  u64* colLds = (u64*)(lds + 8192); // [2 wm][256 cols]  4KB

  // row best: per target row, over this wave's 64 source cols
  #pragma unroll
  for (int m = 0; m < 8; ++m) {
    #pragma unroll
    for (int j = 0; j < 4; ++j) {
      u64 best = 0ull;
      #pragma unroll
      for (int n = 0; n < 4; ++n)
        best = umax(best, packSI(acc[m][n][j], (u32)(tileC + wn * 64 + n * 16 + lcol)));
      #pragma unroll
      for (int s = 1; s < 16; s <<= 1)
        best = umax(best, (u64)__shfl_xor(best, s, 64));
      if (lcol == 0)
        rowLds[wn * 256 + wm * 128 + m * 16 + lrow * 4 + j] = best;
    }
  }
  // col best: per source col, over this wave's 128 target rows
  #pragma unroll
  for (int n = 0; n < 4; ++n) {
    u64 best = 0ull;
    #pragma unroll
    for (int m = 0; m < 8; ++m)
      #pragma unroll
      for (int j = 0; j < 4; ++j)
        best = umax(best, packSI(acc[m][n][j], (u32)(tileR + wm * 128 + m * 16 + lrow * 4 + j)));
    #pragma unroll
    for (int s = 16; s < 64; s <<= 1)
      best = umax(best, (u64)__shfl_xor(best, s, 64));
    if (lrow == 0)
      colLds[wm * 256 + wn * 64 + n * 16 + lcol] = best;
  }
  __syncthreads();
  if (tid < 256) {
    u64 b = rowLds[tid];
    b = umax(b, rowLds[256 + tid]);
    b = umax(b, rowLds[512 + tid]);
    b = umax(b, rowLds[768 + tid]);
    rowPart[(size_t)ct * NPAD2 + tileR + tid] = b;
  } else {
    int c = tid - 256;
    u64 b = umax(colLds[c], colLds[256 + c]);
    colPart[(size_t)rt * NPAD2 + tileC + c] = b;
  }
}

// deterministic max-reduce over the 36 per-tile partials
__global__ __launch_bounds__(256) void k_red(const u64* __restrict__ rowPart,
                                             const u64* __restrict__ colPart,
                                             u64* __restrict__ rowP,
                                             u64* __restrict__ colP) {
  int n = blockIdx.x * 256 + threadIdx.x;   // grid 36 -> 9216
  u64 r = 0ull, c = 0ull;
  for (int i = 0; i < NT2; ++i) {
    u64 a = rowPart[(size_t)i * NPAD2 + n]; if (a > r) r = a;
    u64 b = colPart[(size_t)i * NPAD2 + n]; if (b > c) c = b;
  }
  rowP[n] = r; colP[n] = c;
}

// final losses from packed (score, idx) + squared norms; single block, deterministic
__global__ __launch_bounds__(1024) void k_loss(const u64* __restrict__ rowP,
                                               const u64* __restrict__ colP,
                                               const float* __restrict__ sq_s,
                                               const float* __restrict__ sq_t,
                                               float* __restrict__ out) {
  __shared__ float r0[1024], r1[1024];
  int t = threadIdx.x;
  float lt = 0.f, ls = 0.f;
  for (int n = t; n < NP; n += 1024) {
    {
      u64 p = rowP[n];
      u32 key = (u32)(p >> 32);
      u32 b = (key & 0x80000000u) ? (key ^ 0x80000000u) : ~key;
      float sc = __uint_as_float(b);
      u32 m = ~((u32)p);
      float a = sq_t[n], c = sq_s[m];
      lt += a + c - 2.f * sc * (sqrtf(a) + FEPS) * (sqrtf(c) + FEPS);
    }
    {
      u64 p = colP[n];
      u32 key = (u32)(p >> 32);
      u32 b = (key & 0x80000000u) ? (key ^ 0x80000000u) : ~key;
      float sc = __uint_as_float(b);
      u32 m = ~((u32)p);
      float a = sq_s[n], c = sq_t[m];
      ls += a + c - 2.f * sc * (sqrtf(a) + FEPS) * (sqrtf(c) + FEPS);
    }
  }
  r0[t] = lt; r1[t] = ls;
  __syncthreads();
  for (int s = 512; s > 0; s >>= 1) {
    if (t < s) { r0[t] += r0[t + s]; r1[t] += r1[t + s]; }
    __syncthreads();
  }
  if (t == 0) {
    const float scale = 0.5f / ((float)NP * (float)DD);
    out[0] = r0[0] * scale;   // loss_target
    out[1] = r1[0] * scale;   // loss_source
  }
}

extern "C" void kernel_launch(void* const* d_in, const int* in_sizes, int n_in,
                              void* d_out, int out_size, void* d_ws, size_t ws_size,
                              hipStream_t stream) {
  const float* src = (const float*)d_in[0];
  const float* tgt = (const float*)d_in[1];
  float* out = (float*)d_out;
  char* ws = (char*)d_ws;
  size_t o = 0;
  bf16* Sn = (bf16*)(ws + o); o += (size_t)NPAD2 * DD * 2;
  bf16* Tn = (bf16*)(ws + o); o += (size_t)NPAD2 * DD * 2;
  float* sq_s = (float*)(ws + o); o += (size_t)NPAD2 * 4;
  float* sq_t = (float*)(ws + o); o += (size_t)NPAD2 * 4;
  float* q_s = (float*)(ws + o); o += (size_t)HH * WW * 4;
  float* q_t = (float*)(ws + o); o += (size_t)HH * WW * 4;
  u64* rowPart = (u64*)(ws + o); o += (size_t)NT2 * NPAD2 * 8;
  u64* colPart = (u64*)(ws + o); o += (size_t)NT2 * NPAD2 * 8;
  u64* rowP = (u64*)(ws + o); o += (size_t)NPAD2 * 8;
  u64* colP = (u64*)(ws + o); o += (size_t)NPAD2 * 8;
  if (ws_size < o) return;  // ~43.4 MiB needed

  k_init<<<96, 256, 0, stream>>>(Sn, Tn);
  k_q<<<dim3(36, 2), 256, 0, stream>>>(src, tgt, q_s, q_t);
  k_sq<<<36, 256, 0, stream>>>(q_s, q_t, sq_s, sq_t);
  k_norm<<<dim3(16, PH), 128, 0, stream>>>(src, sq_s, Sn);
  k_norm<<<dim3(16, PH), 128, 0, stream>>>(tgt, sq_t, Tn);
  k_gemm<<<NBLK2, 512, 0, stream>>>(Tn, Sn, rowPart, colPart);
  k_red<<<36, 256, 0, stream>>>(rowPart, colPart, rowP, colP);
  k_loss<<<1, 1024, 0, stream>>>(rowP, colP, sq_s, sq_t, out);
}

// Round 5
// 391.568 us; speedup vs baseline: 1.2089x; 1.0287x over previous
//
#include <hip/hip_runtime.h>
#include <hip/hip_bf16.h>
#include <stdint.h>

#define HH 96
#define WW 96
#define NCH 256
#define PH 95
#define PW 95
#define NP 9025          // PH*PW
#define DD 1024          // 4*NCH
#define FEPS 1e-8f

#define BM 256           // tile M=N
#define BK 64            // K-step
#define NT2 36           // tiles per dim
#define NPAD2 9216       // NT2*BM
#define NBLK2 1296       // NT2*NT2 (divisible by 8)
#define KT 16            // DD/BK

typedef __attribute__((ext_vector_type(8))) short bf16x8;
typedef __attribute__((ext_vector_type(4))) float f32x4;
typedef unsigned long long u64;
typedef unsigned int u32;
using bf16 = __hip_bfloat16;

// monotone float key + inverted index => u64 max == (max score, smallest idx)
__device__ __forceinline__ u64 packSI(float v, u32 idx) {
  u32 b = __float_as_uint(v);
  u32 key = (b & 0x80000000u) ? ~b : (b | 0x80000000u);
  return ((u64)key << 32) | (u64)(~idx);
}
__device__ __forceinline__ u64 umax(u64 a, u64 b) { return a > b ? a : b; }

// zero pad rows NP..NPAD2 of Sn,Tn (so pad scores are exactly 0 and never win)
__global__ __launch_bounds__(256) void k_init(bf16* Sn, bf16* Tn) {
  int i = blockIdx.x * 256 + threadIdx.x;
  const int padWords = (NPAD2 - NP) * DD / 2;  // u32 words
  u32* ps = (u32*)(Sn + (size_t)NP * DD);
  u32* pt = (u32*)(Tn + (size_t)NP * DD);
  for (int j = i; j < padWords; j += gridDim.x * 256) { ps[j] = 0u; pt[j] = 0u; }
}

// per-pixel channel sum of squares
__global__ __launch_bounds__(256) void k_q(const float* __restrict__ src,
                                           const float* __restrict__ tgt,
                                           float* __restrict__ q_s,
                                           float* __restrict__ q_t) {
  int p = blockIdx.x * 256 + threadIdx.x;  // 36*256 == 9216 exactly
  const float* img = blockIdx.y ? tgt : src;
  float acc = 0.f;
  #pragma unroll 8
  for (int c = 0; c < NCH; ++c) {
    float v = img[(size_t)c * (HH * WW) + p];
    acc = fmaf(v, v, acc);
  }
  (blockIdx.y ? q_t : q_s)[p] = acc;
}

// per-patch squared norm = 4-point sum of q
__global__ __launch_bounds__(256) void k_sq(const float* __restrict__ q_s,
                                            const float* __restrict__ q_t,
                                            float* __restrict__ sq_s,
                                            float* __restrict__ sq_t) {
  int n = blockIdx.x * 256 + threadIdx.x;
  if (n >= NP) return;
  int y = n / PW, x = n - y * PW;
  int b = y * WW + x;
  sq_s[n] = q_s[b] + q_s[b + 1] + q_s[b + WW] + q_s[b + WW + 1];
  sq_t[n] = q_t[b] + q_t[b + 1] + q_t[b + WW] + q_t[b + WW + 1];
}

// normalized bf16 patch matrix [NPAD2][DD], written via LDS transpose
__global__ __launch_bounds__(128) void k_norm(const float* __restrict__ img,
                                              const float* __restrict__ sq,
                                              bf16* __restrict__ out) {
  __shared__ float tile[64 * 129];
  __shared__ float rn[PW];
  int y = blockIdx.y;
  int d0 = blockIdx.x * 64;     // 16 chunks of 64 d's
  int k = d0 >> 8;              // which 2x2 shift
  int c0 = d0 & 255;
  int iy = k >> 1, jx = k & 1;
  int t = threadIdx.x;
  if (t < PW) rn[t] = 1.f / (sqrtf(sq[y * PW + t]) + FEPS);
  int x = t;
  const float* base = img + (size_t)(y + iy) * WW + jx;
  #pragma unroll 4
  for (int dl = 0; dl < 64; ++dl) {
    int c = c0 + dl;
    float v = (x < PW) ? base[(size_t)c * (HH * WW) + x] : 0.f;
    tile[dl * 129 + x] = v;
  }
  __syncthreads();
  int dl = t & 63, xh = t >> 6;
  for (int xl = xh; xl < PW; xl += 2) {
    out[(size_t)(y * PW + xl) * DD + d0 + dl] =
        __float2bfloat16(tile[dl * 129 + xl] * rn[xl]);
  }
}

// 256x256-tile bf16 MFMA GEMM (scores = Tn * Sn^T): 4-quadrant-phase schedule
// (T3), counted vmcnt (T4), st-slot XOR swizzle (T2, both-sides), setprio (T5).
// Fused bidirectional argmax -> per-tile partials (no atomics).
// LDS pieces: (dbuf d, matrix M in {A,B}, row-half h) 128x64 bf16 = 16KB each.
__global__ __launch_bounds__(512, 2) void k_gemm(const bf16* __restrict__ Tn,
                                                 const bf16* __restrict__ Sn,
                                                 u64* __restrict__ rowPart,
                                                 u64* __restrict__ colPart) {
  __shared__ __align__(16) char ldsc[131072];  // 128 KiB
  bf16* ldsb = (bf16*)ldsc;

  int bid = blockIdx.x;
  // XCD swizzle: NBLK2 % 8 == 0 -> simple chunked form
  int swz = (bid & 7) * (NBLK2 / 8) + (bid >> 3);
  int rt = swz / NT2, ct = swz % NT2;
  int tileR = rt * BM, tileC = ct * BM;

  int tid = threadIdx.x;
  int lane = tid & 63, wid = tid >> 6;
  int wm = wid >> 2, wn = wid & 3;       // 2 x 4 wave grid; per-wave out 128x64
  int lcol = lane & 15, lrow = lane >> 4;
  int xorv = lcol & 7;                   // read-side swizzle XOR (row&7 == lcol&7)

  const bf16* gA = Tn + (size_t)tileR * DD;
  const bf16* gB = Sn + (size_t)tileC * DD;

  f32x4 acc[8][4] = {};

  // stage all 4 pieces (A0,A1,B0,B1) of K-tile kt into dbuf dpar.
  // linear LDS dest + inverse-swizzled global source column (involution).
  auto STAGE = [&](int dpar, int kt) {
    int k0 = kt * BK;
    #pragma unroll
    for (int M = 0; M < 2; ++M)
      #pragma unroll
      for (int h = 0; h < 2; ++h)
        #pragma unroll
        for (int q = 0; q < 2; ++q) {
          int ch = q * 512 + tid;        // 16-B chunk within 16KB piece
          int r = ch >> 3, s = ch & 7;
          int ldofs = (dpar * 4 + M * 2 + h) * 16384 + ch * 16;
          const bf16* g = (M ? gB : gA) + (size_t)(h * 128 + r) * DD + k0 +
                          ((s ^ (r & 7)) << 3);
          __builtin_amdgcn_global_load_lds(
              (const __attribute__((address_space(1))) void*)g,
              (__attribute__((address_space(3))) void*)(ldsc + ldofs), 16, 0, 0);
        }
  };

  // read the 12 b128 fragments for quadrant p from dbuf dpar (swizzled)
  auto PHASE_READ = [&](int dpar, int p, bf16x8* a8, bf16x8* b8) {
    int qm = p >> 1, qn = p & 1;
    const bf16* pa = ldsb + (dpar * 4 + wm) * 8192;
    const bf16* pb = ldsb + (dpar * 4 + 2 + (wn >> 1)) * 8192;
    #pragma unroll
    for (int m4 = 0; m4 < 4; ++m4) {
      int r = qm * 64 + m4 * 16 + lcol;
      #pragma unroll
      for (int ks = 0; ks < 2; ++ks)
        a8[m4 * 2 + ks] =
            *(const bf16x8*)(pa + r * 64 + (((ks * 4 + lrow) ^ xorv) << 3));
    }
    #pragma unroll
    for (int nf = 0; nf < 2; ++nf) {
      int r = (wn & 1) * 64 + (qn * 2 + nf) * 16 + lcol;
      #pragma unroll
      for (int ks = 0; ks < 2; ++ks)
        b8[nf * 2 + ks] =
            *(const bf16x8*)(pb + r * 64 + (((ks * 4 + lrow) ^ xorv) << 3));
    }
  };

  auto PHASE_MMA = [&](int p, const bf16x8* a8, const bf16x8* b8) {
    int qm = p >> 1, qn = p & 1;
    #pragma unroll
    for (int ks = 0; ks < 2; ++ks)
      #pragma unroll
      for (int m4 = 0; m4 < 4; ++m4)
        #pragma unroll
        for (int nf = 0; nf < 2; ++nf)
          acc[qm * 4 + m4][qn * 2 + nf] = __builtin_amdgcn_mfma_f32_16x16x32_bf16(
              a8[m4 * 2 + ks], b8[nf * 2 + ks], acc[qm * 4 + m4][qn * 2 + nf], 0, 0, 0);
  };

  STAGE(0, 0);
  for (int kt = 0; kt < KT; ++kt) {
    int d = kt & 1;
    bf16x8 a8[8], b8[4];
    // ---- phase 0: prefetch next K-tile, counted wait, then quadrant 0
    if (kt + 1 < KT) {
      STAGE(d ^ 1, kt + 1);
      asm volatile("s_waitcnt vmcnt(8)" ::: "memory");  // current tile landed;
    } else {                                            // prefetch stays in flight
      asm volatile("s_waitcnt vmcnt(0)" ::: "memory");
    }
    __builtin_amdgcn_s_barrier();       // all waves confirmed their loads
    PHASE_READ(d, 0, a8, b8);
    asm volatile("s_waitcnt lgkmcnt(0)" ::: "memory");
    __builtin_amdgcn_sched_barrier(0);  // rule #18: keep MFMA below the wait
    __builtin_amdgcn_s_setprio(1);
    PHASE_MMA(0, a8, b8);
    __builtin_amdgcn_s_setprio(0);
    __builtin_amdgcn_s_barrier();
    // ---- phases 1..3
    #pragma unroll
    for (int p = 1; p < 4; ++p) {
      PHASE_READ(d, p, a8, b8);
      __builtin_amdgcn_s_barrier();
      asm volatile("s_waitcnt lgkmcnt(0)" ::: "memory");
      __builtin_amdgcn_sched_barrier(0);
      __builtin_amdgcn_s_setprio(1);
      PHASE_MMA(p, a8, b8);
      __builtin_amdgcn_s_setprio(0);
      __builtin_amdgcn_s_barrier();
    }
  }

  // ---- epilogue: bidirectional argmax to per-tile partials, no atomics ----
  __syncthreads();                  // full drain; LDS now reusable
  u64* rowLds = (u64*)ldsc;           // [4 wn][256 rows]  8KB
  u64* colLds = (u64*)(ldsc + 8192);  // [2 wm][256 cols]  4KB

  // row best: per target row, over this wave's 64 source cols
  #pragma unroll
  for (int m = 0; m < 8; ++m) {
    #pragma unroll
    for (int j = 0; j < 4; ++j) {
      u64 best = 0ull;
      #pragma unroll
      for (int n = 0; n < 4; ++n)
        best = umax(best, packSI(acc[m][n][j], (u32)(tileC + wn * 64 + n * 16 + lcol)));
      #pragma unroll
      for (int s = 1; s < 16; s <<= 1)
        best = umax(best, (u64)__shfl_xor(best, s, 64));
      if (lcol == 0)
        rowLds[wn * 256 + wm * 128 + m * 16 + lrow * 4 + j] = best;
    }
  }
  // col best: per source col, over this wave's 128 target rows
  #pragma unroll
  for (int n = 0; n < 4; ++n) {
    u64 best = 0ull;
    #pragma unroll
    for (int m = 0; m < 8; ++m)
      #pragma unroll
      for (int j = 0; j < 4; ++j)
        best = umax(best, packSI(acc[m][n][j], (u32)(tileR + wm * 128 + m * 16 + lrow * 4 + j)));
    #pragma unroll
    for (int s = 16; s < 64; s <<= 1)
      best = umax(best, (u64)__shfl_xor(best, s, 64));
    if (lrow == 0)
      colLds[wm * 256 + wn * 64 + n * 16 + lcol] = best;
  }
  __syncthreads();
  if (tid < 256) {
    u64 b = rowLds[tid];
    b = umax(b, rowLds[256 + tid]);
    b = umax(b, rowLds[512 + tid]);
    b = umax(b, rowLds[768 + tid]);
    rowPart[(size_t)ct * NPAD2 + tileR + tid] = b;
  } else {
    int c = tid - 256;
    u64 b = umax(colLds[c], colLds[256 + c]);
    colPart[(size_t)rt * NPAD2 + tileC + c] = b;
  }
}

// deterministic max-reduce over the 36 per-tile partials
__global__ __launch_bounds__(256) void k_red(const u64* __restrict__ rowPart,
                                             const u64* __restrict__ colPart,
                                             u64* __restrict__ rowP,
                                             u64* __restrict__ colP) {
  int n = blockIdx.x * 256 + threadIdx.x;   // grid 36 -> 9216
  u64 r = 0ull, c = 0ull;
  for (int i = 0; i < NT2; ++i) {
    u64 a = rowPart[(size_t)i * NPAD2 + n]; if (a > r) r = a;
    u64 b = colPart[(size_t)i * NPAD2 + n]; if (b > c) c = b;
  }
  rowP[n] = r; colP[n] = c;
}

// final losses from packed (score, idx) + squared norms; single block, deterministic
__global__ __launch_bounds__(1024) void k_loss(const u64* __restrict__ rowP,
                                               const u64* __restrict__ colP,
                                               const float* __restrict__ sq_s,
                                               const float* __restrict__ sq_t,
                                               float* __restrict__ out) {
  __shared__ float r0[1024], r1[1024];
  int t = threadIdx.x;
  float lt = 0.f, ls = 0.f;
  for (int n = t; n < NP; n += 1024) {
    {
      u64 p = rowP[n];
      u32 key = (u32)(p >> 32);
      u32 b = (key & 0x80000000u) ? (key ^ 0x80000000u) : ~key;
      float sc = __uint_as_float(b);
      u32 m = ~((u32)p);
      float a = sq_t[n], c = sq_s[m];
      lt += a + c - 2.f * sc * (sqrtf(a) + FEPS) * (sqrtf(c) + FEPS);
    }
    {
      u64 p = colP[n];
      u32 key = (u32)(p >> 32);
      u32 b = (key & 0x80000000u) ? (key ^ 0x80000000u) : ~key;
      float sc = __uint_as_float(b);
      u32 m = ~((u32)p);
      float a = sq_s[n], c = sq_t[m];
      ls += a + c - 2.f * sc * (sqrtf(a) + FEPS) * (sqrtf(c) + FEPS);
    }
  }
  r0[t] = lt; r1[t] = ls;
  __syncthreads();
  for (int s = 512; s > 0; s >>= 1) {
    if (t < s) { r0[t] += r0[t + s]; r1[t] += r1[t + s]; }
    __syncthreads();
  }
  if (t == 0) {
    const float scale = 0.5f / ((float)NP * (float)DD);
    out[0] = r0[0] * scale;   // loss_target
    out[1] = r1[0] * scale;   // loss_source
  }
}

extern "C" void kernel_launch(void* const* d_in, const int* in_sizes, int n_in,
                              void* d_out, int out_size, void* d_ws, size_t ws_size,
                              hipStream_t stream) {
  const float* src = (const float*)d_in[0];
  const float* tgt = (const float*)d_in[1];
  float* out = (float*)d_out;
  char* ws = (char*)d_ws;
  size_t o = 0;
  bf16* Sn = (bf16*)(ws + o); o += (size_t)NPAD2 * DD * 2;
  bf16* Tn = (bf16*)(ws + o); o += (size_t)NPAD2 * DD * 2;
  float* sq_s = (float*)(ws + o); o += (size_t)NPAD2 * 4;
  float* sq_t = (float*)(ws + o); o += (size_t)NPAD2 * 4;
  float* q_s = (float*)(ws + o); o += (size_t)HH * WW * 4;
  float* q_t = (float*)(ws + o); o += (size_t)HH * WW * 4;
  u64* rowPart = (u64*)(ws + o); o += (size_t)NT2 * NPAD2 * 8;
  u64* colPart = (u64*)(ws + o); o += (size_t)NT2 * NPAD2 * 8;
  u64* rowP = (u64*)(ws + o); o += (size_t)NPAD2 * 8;
  u64* colP = (u64*)(ws + o); o += (size_t)NPAD2 * 8;
  if (ws_size < o) return;  // ~43.4 MiB needed

  k_init<<<96, 256, 0, stream>>>(Sn, Tn);
  k_q<<<dim3(36, 2), 256, 0, stream>>>(src, tgt, q_s, q_t);
  k_sq<<<36, 256, 0, stream>>>(q_s, q_t, sq_s, sq_t);
  k_norm<<<dim3(16, PH), 128, 0, stream>>>(src, sq_s, Sn);
  k_norm<<<dim3(16, PH), 128, 0, stream>>>(tgt, sq_t, Tn);
  k_gemm<<<NBLK2, 512, 0, stream>>>(Tn, Sn, rowPart, colPart);
  k_red<<<36, 256, 0, stream>>>(rowPart, colPart, rowP, colP);
  k_loss<<<1, 1024, 0, stream>>>(rowP, colP, sq_s, sq_t, out);
}

// Round 6
// 349.512 us; speedup vs baseline: 1.3544x; 1.1203x over previous
//
#include <hip/hip_runtime.h>
#include <hip/hip_bf16.h>
#include <stdint.h>

#define HH 96
#define WW 96
#define NCH 256
#define PH 95
#define PW 95
#define NP 9025          // PH*PW
#define DD 1024          // 4*NCH
#define FEPS 1e-8f

#define BM 256           // tile M=N
#define BK 64            // K-step
#define NT2 36           // tiles per dim
#define NPAD2 9216       // NT2*BM
#define NBLK2 1296       // NT2*NT2 (divisible by 8)
#define KT 16            // DD/BK

typedef __attribute__((ext_vector_type(8))) short bf16x8;
typedef __attribute__((ext_vector_type(4))) float f32x4;
typedef unsigned long long u64;
typedef unsigned int u32;
using bf16 = __hip_bfloat16;

// monotone float key + inverted index => u64 max == (max score, smallest idx)
__device__ __forceinline__ u64 packSI(float v, u32 idx) {
  u32 b = __float_as_uint(v);
  u32 key = (b & 0x80000000u) ? ~b : (b | 0x80000000u);
  return ((u64)key << 32) | (u64)(~idx);
}
__device__ __forceinline__ u64 umax(u64 a, u64 b) { return a > b ? a : b; }

// zero pad rows NP..NPAD2 of Sn,Tn (so pad scores are exactly 0 and never win)
__global__ __launch_bounds__(256) void k_init(bf16* Sn, bf16* Tn) {
  int i = blockIdx.x * 256 + threadIdx.x;
  const int padWords = (NPAD2 - NP) * DD / 2;  // u32 words
  u32* ps = (u32*)(Sn + (size_t)NP * DD);
  u32* pt = (u32*)(Tn + (size_t)NP * DD);
  for (int j = i; j < padWords; j += gridDim.x * 256) { ps[j] = 0u; pt[j] = 0u; }
}

// per-pixel channel sum of squares
__global__ __launch_bounds__(256) void k_q(const float* __restrict__ src,
                                           const float* __restrict__ tgt,
                                           float* __restrict__ q_s,
                                           float* __restrict__ q_t) {
  int p = blockIdx.x * 256 + threadIdx.x;  // 36*256 == 9216 exactly
  const float* img = blockIdx.y ? tgt : src;
  float acc = 0.f;
  #pragma unroll 8
  for (int c = 0; c < NCH; ++c) {
    float v = img[(size_t)c * (HH * WW) + p];
    acc = fmaf(v, v, acc);
  }
  (blockIdx.y ? q_t : q_s)[p] = acc;
}

// per-patch squared norm = 4-point sum of q
__global__ __launch_bounds__(256) void k_sq(const float* __restrict__ q_s,
                                            const float* __restrict__ q_t,
                                            float* __restrict__ sq_s,
                                            float* __restrict__ sq_t) {
  int n = blockIdx.x * 256 + threadIdx.x;
  if (n >= NP) return;
  int y = n / PW, x = n - y * PW;
  int b = y * WW + x;
  sq_s[n] = q_s[b] + q_s[b + 1] + q_s[b + WW] + q_s[b + WW + 1];
  sq_t[n] = q_t[b] + q_t[b + 1] + q_t[b + WW] + q_t[b + WW + 1];
}

// normalized bf16 patch matrix [NPAD2][DD], written via LDS transpose
__global__ __launch_bounds__(128) void k_norm(const float* __restrict__ img,
                                              const float* __restrict__ sq,
                                              bf16* __restrict__ out) {
  __shared__ float tile[64 * 129];
  __shared__ float rn[PW];
  int y = blockIdx.y;
  int d0 = blockIdx.x * 64;     // 16 chunks of 64 d's
  int k = d0 >> 8;              // which 2x2 shift
  int c0 = d0 & 255;
  int iy = k >> 1, jx = k & 1;
  int t = threadIdx.x;
  if (t < PW) rn[t] = 1.f / (sqrtf(sq[y * PW + t]) + FEPS);
  int x = t;
  const float* base = img + (size_t)(y + iy) * WW + jx;
  #pragma unroll 4
  for (int dl = 0; dl < 64; ++dl) {
    int c = c0 + dl;
    float v = (x < PW) ? base[(size_t)c * (HH * WW) + x] : 0.f;
    tile[dl * 129 + x] = v;
  }
  __syncthreads();
  int dl = t & 63, xh = t >> 6;
  for (int xl = xh; xl < PW; xl += 2) {
    out[(size_t)(y * PW + xl) * DD + d0 + dl] =
        __float2bfloat16(tile[dl * 129 + xl] * rn[xl]);
  }
}

// 256x256-tile bf16 MFMA GEMM (scores = Tn * Sn^T).
// Schedule: T4 counted vmcnt across K-tiles; within a K-tile 4 MFMA clusters
// pipelined with counted lgkmcnt (reads for cluster p+1 in flight during
// cluster p); each fragment read from LDS exactly once; barriers only at
// K-tile boundaries (2 per tile). T2 16B-slot XOR swizzle (both-sides).
// Fused bidirectional argmax -> per-tile partials (no atomics).
// LDS pieces: (dbuf d, matrix M in {A,B}, row-half h) 128x64 bf16 = 16KB each.
__global__ __launch_bounds__(512, 2) void k_gemm(const bf16* __restrict__ Tn,
                                                 const bf16* __restrict__ Sn,
                                                 u64* __restrict__ rowPart,
                                                 u64* __restrict__ colPart) {
  __shared__ __align__(16) char ldsc[131072];  // 128 KiB
  bf16* ldsb = (bf16*)ldsc;

  int bid = blockIdx.x;
  // XCD swizzle: NBLK2 % 8 == 0 -> simple chunked form
  int swz = (bid & 7) * (NBLK2 / 8) + (bid >> 3);
  int rt = swz / NT2, ct = swz % NT2;
  int tileR = rt * BM, tileC = ct * BM;

  int tid = threadIdx.x;
  int lane = tid & 63, wid = tid >> 6;
  int wm = wid >> 2, wn = wid & 3;       // 2 x 4 wave grid; per-wave out 128x64
  int lcol = lane & 15, lrow = lane >> 4;
  int xorv = lcol & 7;                   // read-side swizzle XOR (row&7 == lcol&7)

  const bf16* gA = Tn + (size_t)tileR * DD;
  const bf16* gB = Sn + (size_t)tileC * DD;

  f32x4 acc[8][4] = {};

  // stage all 4 pieces (A0,A1,B0,B1) of K-tile kt into dbuf dpar.
  // linear LDS dest + inverse-swizzled global source column (involution).
  auto STAGE = [&](int dpar, int kt) {
    int k0 = kt * BK;
    #pragma unroll
    for (int M = 0; M < 2; ++M)
      #pragma unroll
      for (int h = 0; h < 2; ++h)
        #pragma unroll
        for (int q = 0; q < 2; ++q) {
          int ch = q * 512 + tid;        // 16-B chunk within 16KB piece
          int r = ch >> 3, s = ch & 7;
          int ldofs = (dpar * 4 + M * 2 + h) * 16384 + ch * 16;
          const bf16* g = (M ? gB : gA) + (size_t)(h * 128 + r) * DD + k0 +
                          ((s ^ (r & 7)) << 3);
          __builtin_amdgcn_global_load_lds(
              (const __attribute__((address_space(1))) void*)g,
              (__attribute__((address_space(3))) void*)(ldsc + ldofs), 16, 0, 0);
        }
  };

  // 4 A-frags for (qm-half, ks) — each read exactly once per K-tile
  auto READ_A = [&](int dpar, int qm, int ks, bf16x8* a) {
    const bf16* pa = ldsb + (dpar * 4 + wm) * 8192;
    #pragma unroll
    for (int m4 = 0; m4 < 4; ++m4) {
      int r = qm * 64 + m4 * 16 + lcol;
      a[m4] = *(const bf16x8*)(pa + r * 64 + (((ks * 4 + lrow) ^ xorv) << 3));
    }
  };
  auto READ_B = [&](int dpar, int ks, bf16x8* b) {
    const bf16* pb = ldsb + (dpar * 4 + 2 + (wn >> 1)) * 8192;
    #pragma unroll
    for (int n = 0; n < 4; ++n) {
      int r = (wn & 1) * 64 + n * 16 + lcol;
      b[n] = *(const bf16x8*)(pb + r * 64 + (((ks * 4 + lrow) ^ xorv) << 3));
    }
  };
  auto MMA = [&](int qm, const bf16x8* a, const bf16x8* b) {
    #pragma unroll
    for (int m4 = 0; m4 < 4; ++m4)
      #pragma unroll
      for (int n = 0; n < 4; ++n)
        acc[qm * 4 + m4][n] = __builtin_amdgcn_mfma_f32_16x16x32_bf16(
            a[m4], b[n], acc[qm * 4 + m4][n], 0, 0, 0);
  };

  STAGE(0, 0);
  for (int kt = 0; kt < KT; ++kt) {
    int d = kt & 1;
    if (kt + 1 < KT) {
      STAGE(d ^ 1, kt + 1);                             // prefetch next K-tile
      asm volatile("s_waitcnt vmcnt(8)" ::: "memory");  // tile kt landed;
    } else {                                            // prefetch in flight
      asm volatile("s_waitcnt vmcnt(0)" ::: "memory");
    }
    __builtin_amdgcn_s_barrier();       // all waves confirmed their loads

    bf16x8 b0[4], b1[4], aE[4], aO[4];
    READ_B(d, 0, b0);                   //  4 ds_read
    READ_A(d, 0, 0, aE);                //  8 outstanding
    READ_A(d, 1, 0, aO);                // 12 outstanding
    asm volatile("s_waitcnt lgkmcnt(4)" ::: "memory");  // b0,aE ready
    __builtin_amdgcn_sched_barrier(0);
    __builtin_amdgcn_s_setprio(1);
    MMA(0, aE, b0);
    __builtin_amdgcn_s_setprio(0);
    READ_B(d, 1, b1);
    READ_A(d, 0, 1, aE);                // reuse aE (compiler orders WAR)
    asm volatile("s_waitcnt lgkmcnt(8)" ::: "memory");  // aO ready
    __builtin_amdgcn_sched_barrier(0);
    __builtin_amdgcn_s_setprio(1);
    MMA(1, aO, b0);
    __builtin_amdgcn_s_setprio(0);
    READ_A(d, 1, 1, aO);                // reuse aO
    asm volatile("s_waitcnt lgkmcnt(4)" ::: "memory");  // b1,aE ready
    __builtin_amdgcn_sched_barrier(0);
    __builtin_amdgcn_s_setprio(1);
    MMA(0, aE, b1);
    __builtin_amdgcn_s_setprio(0);
    asm volatile("s_waitcnt lgkmcnt(0)" ::: "memory");  // aO ready
    __builtin_amdgcn_sched_barrier(0);
    __builtin_amdgcn_s_setprio(1);
    MMA(1, aO, b1);
    __builtin_amdgcn_s_setprio(0);
    __builtin_amdgcn_s_barrier();       // all waves done with buffer d
  }

  // ---- epilogue: bidirectional argmax to per-tile partials, no atomics ----
  __syncthreads();                  // full drain; LDS now reusable
  u64* rowLds = (u64*)ldsc;           // [4 wn][256 rows]  8KB
  u64* colLds = (u64*)(ldsc + 8192);  // [2 wm][256 cols]  4KB

  // row best: per target row, over this wave's 64 source cols
  #pragma unroll
  for (int m = 0; m < 8; ++m) {
    #pragma unroll
    for (int j = 0; j < 4; ++j) {
      u64 best = 0ull;
      #pragma unroll
      for (int n = 0; n < 4; ++n)
        best = umax(best, packSI(acc[m][n][j], (u32)(tileC + wn * 64 + n * 16 + lcol)));
      #pragma unroll
      for (int s = 1; s < 16; s <<= 1)
        best = umax(best, (u64)__shfl_xor(best, s, 64));
      if (lcol == 0)
        rowLds[wn * 256 + wm * 128 + m * 16 + lrow * 4 + j] = best;
    }
  }
  // col best: per source col, over this wave's 128 target rows
  #pragma unroll
  for (int n = 0; n < 4; ++n) {
    u64 best = 0ull;
    #pragma unroll
    for (int m = 0; m < 8; ++m)
      #pragma unroll
      for (int j = 0; j < 4; ++j)
        best = umax(best, packSI(acc[m][n][j], (u32)(tileR + wm * 128 + m * 16 + lrow * 4 + j)));
    #pragma unroll
    for (int s = 16; s < 64; s <<= 1)
      best = umax(best, (u64)__shfl_xor(best, s, 64));
    if (lrow == 0)
      colLds[wm * 256 + wn * 64 + n * 16 + lcol] = best;
  }
  __syncthreads();
  if (tid < 256) {
    u64 b = rowLds[tid];
    b = umax(b, rowLds[256 + tid]);
    b = umax(b, rowLds[512 + tid]);
    b = umax(b, rowLds[768 + tid]);
    rowPart[(size_t)ct * NPAD2 + tileR + tid] = b;
  } else {
    int c = tid - 256;
    u64 b = umax(colLds[c], colLds[256 + c]);
    colPart[(size_t)rt * NPAD2 + tileC + c] = b;
  }
}

// deterministic max-reduce over the 36 per-tile partials
__global__ __launch_bounds__(256) void k_red(const u64* __restrict__ rowPart,
                                             const u64* __restrict__ colPart,
                                             u64* __restrict__ rowP,
                                             u64* __restrict__ colP) {
  int n = blockIdx.x * 256 + threadIdx.x;   // grid 36 -> 9216
  u64 r = 0ull, c = 0ull;
  for (int i = 0; i < NT2; ++i) {
    u64 a = rowPart[(size_t)i * NPAD2 + n]; if (a > r) r = a;
    u64 b = colPart[(size_t)i * NPAD2 + n]; if (b > c) c = b;
  }
  rowP[n] = r; colP[n] = c;
}

// final losses from packed (score, idx) + squared norms; single block, deterministic
__global__ __launch_bounds__(1024) void k_loss(const u64* __restrict__ rowP,
                                               const u64* __restrict__ colP,
                                               const float* __restrict__ sq_s,
                                               const float* __restrict__ sq_t,
                                               float* __restrict__ out) {
  __shared__ float r0[1024], r1[1024];
  int t = threadIdx.x;
  float lt = 0.f, ls = 0.f;
  for (int n = t; n < NP; n += 1024) {
    {
      u64 p = rowP[n];
      u32 key = (u32)(p >> 32);
      u32 b = (key & 0x80000000u) ? (key ^ 0x80000000u) : ~key;
      float sc = __uint_as_float(b);
      u32 m = ~((u32)p);
      float a = sq_t[n], c = sq_s[m];
      lt += a + c - 2.f * sc * (sqrtf(a) + FEPS) * (sqrtf(c) + FEPS);
    }
    {
      u64 p = colP[n];
      u32 key = (u32)(p >> 32);
      u32 b = (key & 0x80000000u) ? (key ^ 0x80000000u) : ~key;
      float sc = __uint_as_float(b);
      u32 m = ~((u32)p);
      float a = sq_s[n], c = sq_t[m];
      ls += a + c - 2.f * sc * (sqrtf(a) + FEPS) * (sqrtf(c) + FEPS);
    }
  }
  r0[t] = lt; r1[t] = ls;
  __syncthreads();
  for (int s = 512; s > 0; s >>= 1) {
    if (t < s) { r0[t] += r0[t + s]; r1[t] += r1[t + s]; }
    __syncthreads();
  }
  if (t == 0) {
    const float scale = 0.5f / ((float)NP * (float)DD);
    out[0] = r0[0] * scale;   // loss_target
    out[1] = r1[0] * scale;   // loss_source
  }
}

extern "C" void kernel_launch(void* const* d_in, const int* in_sizes, int n_in,
                              void* d_out, int out_size, void* d_ws, size_t ws_size,
                              hipStream_t stream) {
  const float* src = (const float*)d_in[0];
  const float* tgt = (const float*)d_in[1];
  float* out = (float*)d_out;
  char* ws = (char*)d_ws;
  size_t o = 0;
  bf16* Sn = (bf16*)(ws + o); o += (size_t)NPAD2 * DD * 2;
  bf16* Tn = (bf16*)(ws + o); o += (size_t)NPAD2 * DD * 2;
  float* sq_s = (float*)(ws + o); o += (size_t)NPAD2 * 4;
  float* sq_t = (float*)(ws + o); o += (size_t)NPAD2 * 4;
  float* q_s = (float*)(ws + o); o += (size_t)HH * WW * 4;
  float* q_t = (float*)(ws + o); o += (size_t)HH * WW * 4;
  u64* rowPart = (u64*)(ws + o); o += (size_t)NT2 * NPAD2 * 8;
  u64* colPart = (u64*)(ws + o); o += (size_t)NT2 * NPAD2 * 8;
  u64* rowP = (u64*)(ws + o); o += (size_t)NPAD2 * 8;
  u64* colP = (u64*)(ws + o); o += (size_t)NPAD2 * 8;
  if (ws_size < o) return;  // ~43.4 MiB needed

  k_init<<<96, 256, 0, stream>>>(Sn, Tn);
  k_q<<<dim3(36, 2), 256, 0, stream>>>(src, tgt, q_s, q_t);
  k_sq<<<36, 256, 0, stream>>>(q_s, q_t, sq_s, sq_t);
  k_norm<<<dim3(16, PH), 128, 0, stream>>>(src, sq_s, Sn);
  k_norm<<<dim3(16, PH), 128, 0, stream>>>(tgt, sq_t, Tn);
  k_gemm<<<NBLK2, 512, 0, stream>>>(Tn, Sn, rowPart, colPart);
  k_red<<<36, 256, 0, stream>>>(rowPart, colPart, rowP, colP);
  k_loss<<<1, 1024, 0, stream>>>(rowP, colP, sq_s, sq_t, out);
}

// Round 7
// 315.851 us; speedup vs baseline: 1.4987x; 1.1066x over previous
//
#include <hip/hip_runtime.h>
#include <hip/hip_bf16.h>
#include <stdint.h>

#define HH 96
#define WW 96
#define NCH 256
#define PH 95
#define PW 95
#define NP 9025          // PH*PW
#define DD 1024          // 4*NCH
#define FEPS 1e-8f

#define BM 256           // tile M=N
#define BK 64            // K-step
#define NT2 36           // tiles per dim
#define NPAD2 9216       // NT2*BM
#define NBLK2 1296       // NT2*NT2 (divisible by 8)
#define KT 16            // DD/BK

typedef __attribute__((ext_vector_type(8))) short bf16x8;
typedef __attribute__((ext_vector_type(4))) float f32x4;
typedef unsigned long long u64;
typedef unsigned int u32;
using bf16 = __hip_bfloat16;

// monotone float key + inverted index => u64 max == (max score, smallest idx)
__device__ __forceinline__ u64 packSI(float v, u32 idx) {
  u32 b = __float_as_uint(v);
  u32 key = (b & 0x80000000u) ? ~b : (b | 0x80000000u);
  return ((u64)key << 32) | (u64)(~idx);
}
__device__ __forceinline__ u64 umax(u64 a, u64 b) { return a > b ? a : b; }

// per-pixel channel sum of squares; also zeroes pad rows of Sn/Tn
__global__ __launch_bounds__(256) void k_q(const float* __restrict__ src,
                                           const float* __restrict__ tgt,
                                           float* __restrict__ q_s,
                                           float* __restrict__ q_t,
                                           bf16* __restrict__ Sn,
                                           bf16* __restrict__ Tn) {
  int p = blockIdx.x * 256 + threadIdx.x;  // 36*256 == 9216 exactly
  const float* img = blockIdx.y ? tgt : src;
  float acc = 0.f;
  #pragma unroll 8
  for (int c = 0; c < NCH; ++c) {
    float v = img[(size_t)c * (HH * WW) + p];
    acc = fmaf(v, v, acc);
  }
  (blockIdx.y ? q_t : q_s)[p] = acc;
  // zero pad rows NP..NPAD2 (so pad scores are exactly 0 and never win)
  const int padWords = (NPAD2 - NP) * DD / 2;  // u32 words
  u32* pw = (u32*)((blockIdx.y ? Tn : Sn) + (size_t)NP * DD);
  for (int j = p; j < padWords; j += 36 * 256) pw[j] = 0u;
}

// per-patch squared norm = 4-point sum of q
__global__ __launch_bounds__(256) void k_sq(const float* __restrict__ q_s,
                                            const float* __restrict__ q_t,
                                            float* __restrict__ sq_s,
                                            float* __restrict__ sq_t) {
  int n = blockIdx.x * 256 + threadIdx.x;
  if (n >= NP) return;
  int y = n / PW, x = n - y * PW;
  int b = y * WW + x;
  sq_s[n] = q_s[b] + q_s[b + 1] + q_s[b + WW] + q_s[b + WW + 1];
  sq_t[n] = q_t[b] + q_t[b + 1] + q_t[b + WW] + q_t[b + WW + 1];
}

// normalized bf16 patch matrix [NPAD2][DD], written via LDS transpose
// z = 0: (src, sq_s) -> Sn ; z = 1: (tgt, sq_t) -> Tn
__global__ __launch_bounds__(128) void k_norm(const float* __restrict__ src,
                                              const float* __restrict__ tgt,
                                              const float* __restrict__ sq_s,
                                              const float* __restrict__ sq_t,
                                              bf16* __restrict__ Sn,
                                              bf16* __restrict__ Tn) {
  __shared__ float tile[64 * 129];
  __shared__ float rn[PW];
  const float* img = blockIdx.z ? tgt : src;
  const float* sq = blockIdx.z ? sq_t : sq_s;
  bf16* out = blockIdx.z ? Tn : Sn;
  int y = blockIdx.y;
  int d0 = blockIdx.x * 64;     // 16 chunks of 64 d's
  int k = d0 >> 8;              // which 2x2 shift
  int c0 = d0 & 255;
  int iy = k >> 1, jx = k & 1;
  int t = threadIdx.x;
  if (t < PW) rn[t] = 1.f / (sqrtf(sq[y * PW + t]) + FEPS);
  int x = t;
  const float* base = img + (size_t)(y + iy) * WW + jx;
  #pragma unroll 4
  for (int dl = 0; dl < 64; ++dl) {
    int c = c0 + dl;
    float v = (x < PW) ? base[(size_t)c * (HH * WW) + x] : 0.f;
    tile[dl * 129 + x] = v;
  }
  __syncthreads();
  int dl = t & 63, xh = t >> 6;
  for (int xl = xh; xl < PW; xl += 2) {
    out[(size_t)(y * PW + xl) * DD + d0 + dl] =
        __float2bfloat16(tile[dl * 129 + xl] * rn[xl]);
  }
}

// 256x256-tile bf16 MFMA GEMM (scores = Tn * Sn^T), m201-style 8-phase
// schedule: per phase {ds_read subtile || stage 1 half-tile || barrier ||
// lgkm(0) || setprio 16xMFMA || barrier}; counted vmcnt(2) at phases 3,7;
// T2 both-sides XOR swizzle. Fused bidirectional argmax -> per-tile partials.
// LDS: [dbuf 2][piece: A0,A1,B0,B1][128 rows][64 bf16] = 128 KiB.
// K-tile t lives in dbuf (t&1); phases 0-3 compute tile 2i, 4-7 tile 2i+1.
__global__ __launch_bounds__(512, 2) void k_gemm(const bf16* __restrict__ Tn,
                                                 const bf16* __restrict__ Sn,
                                                 u64* __restrict__ rowPart,
                                                 u64* __restrict__ colPart) {
  __shared__ __align__(16) char ldsc[131072];  // 128 KiB
  bf16* ldsb = (bf16*)ldsc;

  int bid = blockIdx.x;
  // XCD swizzle: NBLK2 % 8 == 0 -> simple chunked form
  int swz = (bid & 7) * (NBLK2 / 8) + (bid >> 3);
  int rt = swz / NT2, ct = swz % NT2;
  int tileR = rt * BM, tileC = ct * BM;

  int tid = threadIdx.x;
  int lane = tid & 63, wid = tid >> 6;
  int wm = wid >> 2, wn = wid & 3;       // 2 x 4 wave grid; per-wave out 128x64
  int lcol = lane & 15, lrow = lane >> 4;

  const bf16* gA = Tn + (size_t)tileR * DD;
  const bf16* gB = Sn + (size_t)tileC * DD;

  f32x4 acc[8][4] = {};

  // stage one half-tile (piece pc: 0=A0,1=A1,2=B0,3=B1) of K-tile t, dbuf db.
  // linear LDS dest + inverse-swizzled global source column (involution).
  auto STAGE1 = [&](int db, int t, int pc) {
    int M = pc >> 1, h = pc & 1;
    int k0 = t * BK;
    const bf16* gsrc = M ? gB : gA;
    #pragma unroll
    for (int q2 = 0; q2 < 2; ++q2) {
      int ch = q2 * 512 + tid;           // 16-B chunk within 16KB piece
      int r = ch >> 3, s = ch & 7;
      int ldofs = (db * 4 + pc) * 16384 + ch * 16;
      const bf16* g = gsrc + (size_t)(h * 128 + r) * DD + k0 + ((s ^ (r & 7)) << 3);
      __builtin_amdgcn_global_load_lds(
          (const __attribute__((address_space(1))) void*)g,
          (__attribute__((address_space(3))) void*)(ldsc + ldofs), 16, 0, 0);
    }
  };

  // all 8 A-frags for one ks (swizzled read)
  auto READ_A = [&](int db, int ks, bf16x8* a) {
    const bf16* pa = ldsb + (db * 4 + wm) * 8192;
    #pragma unroll
    for (int m = 0; m < 8; ++m) {
      int r = m * 16 + lcol;
      int c = ks * 4 + lrow;
      a[m] = *(const bf16x8*)(pa + r * 64 + ((c ^ (r & 7)) << 3));
    }
  };
  // 2 B-frags for (ks, nh)
  auto READ_B2 = [&](int db, int ks, int nh, bf16x8* b) {
    const bf16* pb = ldsb + (db * 4 + 2 + (wn >> 1)) * 8192;
    #pragma unroll
    for (int n = 0; n < 2; ++n) {
      int r = (wn & 1) * 64 + (nh * 2 + n) * 16 + lcol;
      int c = ks * 4 + lrow;
      b[n] = *(const bf16x8*)(pb + r * 64 + ((c ^ (r & 7)) << 3));
    }
  };
  auto MMA16 = [&](int nh, const bf16x8* a, const bf16x8* b) {
    #pragma unroll
    for (int m = 0; m < 8; ++m)
      #pragma unroll
      for (int n = 0; n < 2; ++n)
        acc[m][nh * 2 + n] = __builtin_amdgcn_mfma_f32_16x16x32_bf16(
            a[m], b[n], acc[m][nh * 2 + n], 0, 0, 0);
  };

  // ---- prologue: tile 0 (all 4 pieces) + tile 1's A0; prime the ring
  #pragma unroll
  for (int pc = 0; pc < 4; ++pc) STAGE1(0, 0, pc);
  STAGE1(1, 1, 0);
  asm volatile("s_waitcnt vmcnt(2)" ::: "memory");   // tile 0 landed
  __builtin_amdgcn_s_barrier();

  bf16x8 a[8], b[2];
  for (int it = 0; it < KT / 2; ++it) {
    #pragma unroll
    for (int j = 0; j < 8; ++j) {
      const int ks = (j >> 1) & 1, nh = j & 1, pcur = j >> 2;  // dbuf == j>>2
      // --- ds-read this phase's register subtile (from current tile's dbuf)
      if (nh == 0) READ_A(pcur, ks, a);          // 8 x ds_read_b128
      READ_B2(pcur, ks, nh, b);                  // 2 x ds_read_b128
      // --- stage one half-tile into the piece that just died (ring)
      int st_t, st_pc;
      if (j < 3)      { st_t = 2 * it + 1; st_pc = j + 1; }  // A1,B0,B1 of 2i+1
      else if (j < 7) { st_t = 2 * it + 2; st_pc = j - 3; }  // A0..B1 of 2i+2
      else            { st_t = 2 * it + 3; st_pc = 0;     }  // A0 of 2i+3
      if (st_t < KT) STAGE1(st_t & 1, st_t, st_pc);
      // --- counted vmcnt, only at phases 3 and 7 (tail iter drains)
      if (j == 3 || j == 7) {
        if (it == KT / 2 - 1) asm volatile("s_waitcnt vmcnt(0)" ::: "memory");
        else                  asm volatile("s_waitcnt vmcnt(2)" ::: "memory");
      }
      __builtin_amdgcn_s_barrier();
      asm volatile("s_waitcnt lgkmcnt(0)" ::: "memory");
      __builtin_amdgcn_sched_barrier(0);         // keep MFMA below the wait
      __builtin_amdgcn_s_setprio(1);
      MMA16(nh, a, b);
      __builtin_amdgcn_s_setprio(0);
      __builtin_amdgcn_s_barrier();
    }
  }

  // ---- epilogue: bidirectional argmax to per-tile partials, no atomics ----
  __syncthreads();                  // full drain; LDS now reusable
  u64* rowLds = (u64*)ldsc;           // [4 wn][256 rows]  8KB
  u64* colLds = (u64*)(ldsc + 8192);  // [2 wm][256 cols]  4KB

  // row best: per target row, over this wave's 64 source cols
  #pragma unroll
  for (int m = 0; m < 8; ++m) {
    #pragma unroll
    for (int j = 0; j < 4; ++j) {
      u64 best = 0ull;
      #pragma unroll
      for (int n = 0; n < 4; ++n)
        best = umax(best, packSI(acc[m][n][j], (u32)(tileC + wn * 64 + n * 16 + lcol)));
      #pragma unroll
      for (int s = 1; s < 16; s <<= 1)
        best = umax(best, (u64)__shfl_xor(best, s, 64));
      if (lcol == 0)
        rowLds[wn * 256 + wm * 128 + m * 16 + lrow * 4 + j] = best;
    }
  }
  // col best: per source col, over this wave's 128 target rows
  #pragma unroll
  for (int n = 0; n < 4; ++n) {
    u64 best = 0ull;
    #pragma unroll
    for (int m = 0; m < 8; ++m)
      #pragma unroll
      for (int j = 0; j < 4; ++j)
        best = umax(best, packSI(acc[m][n][j], (u32)(tileR + wm * 128 + m * 16 + lrow * 4 + j)));
    #pragma unroll
    for (int s = 16; s < 64; s <<= 1)
      best = umax(best, (u64)__shfl_xor(best, s, 64));
    if (lrow == 0)
      colLds[wm * 256 + wn * 64 + n * 16 + lcol] = best;
  }
  __syncthreads();
  if (tid < 256) {
    u64 b2 = rowLds[tid];
    b2 = umax(b2, rowLds[256 + tid]);
    b2 = umax(b2, rowLds[512 + tid]);
    b2 = umax(b2, rowLds[768 + tid]);
    rowPart[(size_t)ct * NPAD2 + tileR + tid] = b2;
  } else {
    int c = tid - 256;
    u64 b2 = umax(colLds[c], colLds[256 + c]);
    colPart[(size_t)rt * NPAD2 + tileC + c] = b2;
  }
}

// per-n max over 36 tile-partials + analytic loss contributions -> per-block sums
__global__ __launch_bounds__(256) void k_redloss(const u64* __restrict__ rowPart,
                                                 const u64* __restrict__ colPart,
                                                 const float* __restrict__ sq_s,
                                                 const float* __restrict__ sq_t,
                                                 float* __restrict__ part) {
  __shared__ float r0[256], r1[256];
  int t = threadIdx.x;
  int n = blockIdx.x * 256 + t;   // grid 36 -> 9216
  float lt = 0.f, ls = 0.f;
  u64 r = 0ull, c = 0ull;
  for (int i = 0; i < NT2; ++i) {
    u64 x = rowPart[(size_t)i * NPAD2 + n]; if (x > r) r = x;
    u64 y = colPart[(size_t)i * NPAD2 + n]; if (y > c) c = y;
  }
  if (n < NP) {
    {
      u32 key = (u32)(r >> 32);
      u32 bb = (key & 0x80000000u) ? (key ^ 0x80000000u) : ~key;
      float sc = __uint_as_float(bb);
      u32 m = ~((u32)r);
      float a = sq_t[n], cc = sq_s[m];
      lt = a + cc - 2.f * sc * (sqrtf(a) + FEPS) * (sqrtf(cc) + FEPS);
    }
    {
      u32 key = (u32)(c >> 32);
      u32 bb = (key & 0x80000000u) ? (key ^ 0x80000000u) : ~key;
      float sc = __uint_as_float(bb);
      u32 m = ~((u32)c);
      float a = sq_s[n], cc = sq_t[m];
      ls = a + cc - 2.f * sc * (sqrtf(a) + FEPS) * (sqrtf(cc) + FEPS);
    }
  }
  r0[t] = lt; r1[t] = ls;
  __syncthreads();
  for (int s = 128; s > 0; s >>= 1) {
    if (t < s) { r0[t] += r0[t + s]; r1[t] += r1[t + s]; }
    __syncthreads();
  }
  if (t == 0) { part[blockIdx.x * 2] = r0[0]; part[blockIdx.x * 2 + 1] = r1[0]; }
}

// deterministic final sum of the 36 per-block partials
__global__ __launch_bounds__(64) void k_fin(const float* __restrict__ part,
                                            float* __restrict__ out) {
  int l = threadIdx.x;
  float lt = (l < NT2) ? part[l * 2] : 0.f;
  float ls = (l < NT2) ? part[l * 2 + 1] : 0.f;
  #pragma unroll
  for (int s = 1; s < 64; s <<= 1) {
    lt += __shfl_xor(lt, s, 64);
    ls += __shfl_xor(ls, s, 64);
  }
  if (l == 0) {
    const float scale = 0.5f / ((float)NP * (float)DD);
    out[0] = lt * scale;   // loss_target
    out[1] = ls * scale;   // loss_source
  }
}

extern "C" void kernel_launch(void* const* d_in, const int* in_sizes, int n_in,
                              void* d_out, int out_size, void* d_ws, size_t ws_size,
                              hipStream_t stream) {
  const float* src = (const float*)d_in[0];
  const float* tgt = (const float*)d_in[1];
  float* out = (float*)d_out;
  char* ws = (char*)d_ws;
  size_t o = 0;
  bf16* Sn = (bf16*)(ws + o); o += (size_t)NPAD2 * DD * 2;
  bf16* Tn = (bf16*)(ws + o); o += (size_t)NPAD2 * DD * 2;
  float* sq_s = (float*)(ws + o); o += (size_t)NPAD2 * 4;
  float* sq_t = (float*)(ws + o); o += (size_t)NPAD2 * 4;
  float* q_s = (float*)(ws + o); o += (size_t)HH * WW * 4;
  float* q_t = (float*)(ws + o); o += (size_t)HH * WW * 4;
  u64* rowPart = (u64*)(ws + o); o += (size_t)NT2 * NPAD2 * 8;
  u64* colPart = (u64*)(ws + o); o += (size_t)NT2 * NPAD2 * 8;
  float* part = (float*)(ws + o); o += 1024;
  if (ws_size < o) return;  // ~43 MiB needed

  k_q<<<dim3(36, 2), 256, 0, stream>>>(src, tgt, q_s, q_t, Sn, Tn);
  k_sq<<<36, 256, 0, stream>>>(q_s, q_t, sq_s, sq_t);
  k_norm<<<dim3(16, PH, 2), 128, 0, stream>>>(src, tgt, sq_s, sq_t, Sn, Tn);
  k_gemm<<<NBLK2, 512, 0, stream>>>(Tn, Sn, rowPart, colPart);
  k_redloss<<<36, 256, 0, stream>>>(rowPart, colPart, sq_s, sq_t, part);
  k_fin<<<1, 64, 0, stream>>>(part, out);
}

// Round 8
// 310.958 us; speedup vs baseline: 1.5223x; 1.0157x over previous
//
#include <hip/hip_runtime.h>
#include <hip/hip_bf16.h>
#include <stdint.h>

#define HH 96
#define WW 96
#define NCH 256
#define PH 95
#define PW 95
#define NP 9025          // PH*PW
#define DD 1024          // 4*NCH
#define FEPS 1e-8f

#define BM 256           // tile M=N
#define BK 64            // K-step
#define NT2 36           // tiles per dim
#define NPAD2 9216       // NT2*BM
#define NBLK2 1296       // NT2*NT2 (divisible by 8)
#define KT 16            // DD/BK

typedef __attribute__((ext_vector_type(8))) short bf16x8;
typedef __attribute__((ext_vector_type(4))) float f32x4;
typedef unsigned long long u64;
typedef unsigned int u32;
using bf16 = __hip_bfloat16;

// monotone float key + inverted index => u64 max == (max score, smallest idx)
__device__ __forceinline__ u64 packSI(float v, u32 idx) {
  u32 b = __float_as_uint(v);
  u32 key = (b & 0x80000000u) ? ~b : (b | 0x80000000u);
  return ((u64)key << 32) | (u64)(~idx);
}
__device__ __forceinline__ u64 umax(u64 a, u64 b) { return a > b ? a : b; }

// per-pixel channel sum of squares; also zeroes pad rows of Sn/Tn
__global__ __launch_bounds__(256) void k_q(const float* __restrict__ src,
                                           const float* __restrict__ tgt,
                                           float* __restrict__ q_s,
                                           float* __restrict__ q_t,
                                           bf16* __restrict__ Sn,
                                           bf16* __restrict__ Tn) {
  int p = blockIdx.x * 256 + threadIdx.x;  // 36*256 == 9216 exactly
  const float* img = blockIdx.y ? tgt : src;
  float acc = 0.f;
  #pragma unroll 8
  for (int c = 0; c < NCH; ++c) {
    float v = img[(size_t)c * (HH * WW) + p];
    acc = fmaf(v, v, acc);
  }
  (blockIdx.y ? q_t : q_s)[p] = acc;
  // zero pad rows NP..NPAD2 (so pad scores are exactly 0 and never win)
  const int padWords = (NPAD2 - NP) * DD / 2;  // u32 words
  u32* pw = (u32*)((blockIdx.y ? Tn : Sn) + (size_t)NP * DD);
  for (int j = p; j < padWords; j += 36 * 256) pw[j] = 0u;
}

// per-patch squared norm = 4-point sum of q
__global__ __launch_bounds__(256) void k_sq(const float* __restrict__ q_s,
                                            const float* __restrict__ q_t,
                                            float* __restrict__ sq_s,
                                            float* __restrict__ sq_t) {
  int n = blockIdx.x * 256 + threadIdx.x;
  if (n >= NP) return;
  int y = n / PW, x = n - y * PW;
  int b = y * WW + x;
  sq_s[n] = q_s[b] + q_s[b + 1] + q_s[b + WW] + q_s[b + WW + 1];
  sq_t[n] = q_t[b] + q_t[b + 1] + q_t[b + WW] + q_t[b + WW + 1];
}

// normalized bf16 patch matrix [NPAD2][DD], written via LDS transpose
// z = 0: (src, sq_s) -> Sn ; z = 1: (tgt, sq_t) -> Tn
__global__ __launch_bounds__(128) void k_norm(const float* __restrict__ src,
                                              const float* __restrict__ tgt,
                                              const float* __restrict__ sq_s,
                                              const float* __restrict__ sq_t,
                                              bf16* __restrict__ Sn,
                                              bf16* __restrict__ Tn) {
  __shared__ float tile[64 * 129];
  __shared__ float rn[PW];
  const float* img = blockIdx.z ? tgt : src;
  const float* sq = blockIdx.z ? sq_t : sq_s;
  bf16* out = blockIdx.z ? Tn : Sn;
  int y = blockIdx.y;
  int d0 = blockIdx.x * 64;     // 16 chunks of 64 d's
  int k = d0 >> 8;              // which 2x2 shift
  int c0 = d0 & 255;
  int iy = k >> 1, jx = k & 1;
  int t = threadIdx.x;
  if (t < PW) rn[t] = 1.f / (sqrtf(sq[y * PW + t]) + FEPS);
  int x = t;
  const float* base = img + (size_t)(y + iy) * WW + jx;
  #pragma unroll 4
  for (int dl = 0; dl < 64; ++dl) {
    int c = c0 + dl;
    float v = (x < PW) ? base[(size_t)c * (HH * WW) + x] : 0.f;
    tile[dl * 129 + x] = v;
  }
  __syncthreads();
  int dl = t & 63, xh = t >> 6;
  for (int xl = xh; xl < PW; xl += 2) {
    out[(size_t)(y * PW + xl) * DD + d0 + dl] =
        __float2bfloat16(tile[dl * 129 + xl] * rn[xl]);
  }
}

// ---- inline-asm helpers for the GEMM schedule ----
#define DSR(dst, base, IMMSTR) \
  asm volatile("ds_read_b128 %0, %1 offset:" IMMSTR : "=v"(dst) : "v"(base))
#define WAITL(NSTR) asm volatile("s_waitcnt lgkmcnt(" NSTR ")" ::: "memory")
#define SB0 __builtin_amdgcn_sched_barrier(0)

// 256x256-tile bf16 MFMA GEMM (scores = Tn * Sn^T).
// 8 phases / 2 K-tiles; ONE barrier per phase; per heavy phase the 10 ds_reads
// are issued as ordered inline asm (base VGPR + imm offsets) and consumed with
// STAGGERED lgkmcnt(7-m) waits so MFMA overlaps LDS delivery (never drain-0
// until the last fragment). Counted vmcnt(2) after MFMA at phases 3,7.
// T2 both-sides XOR swizzle; T5 setprio. Fused argmax -> per-tile partials.
// LDS: [dbuf 2][piece: A0,A1,B0,B1][128 rows][64 bf16] = 128 KiB.
__global__ __launch_bounds__(512, 2) void k_gemm(const bf16* __restrict__ Tn,
                                                 const bf16* __restrict__ Sn,
                                                 u64* __restrict__ rowPart,
                                                 u64* __restrict__ colPart) {
  __shared__ __align__(16) char ldsc[131072];  // 128 KiB

  int bid = blockIdx.x;
  // XCD swizzle: NBLK2 % 8 == 0 -> simple chunked form
  int swz = (bid & 7) * (NBLK2 / 8) + (bid >> 3);
  int rt = swz / NT2, ct = swz % NT2;
  int tileR = rt * BM, tileC = ct * BM;

  int tid = threadIdx.x;
  int lane = tid & 63, wid = tid >> 6;
  int wm = wid >> 2, wn = wid & 3;       // 2 x 4 wave grid; per-wave out 128x64
  int lcol = lane & 15, lrow = lane >> 4;

  const bf16* gA = Tn + (size_t)tileR * DD;
  const bf16* gB = Sn + (size_t)tileC * DD;

  f32x4 acc[8][4] = {};

  // precomputed LDS byte bases: swizzle term ((ks*4+lrow)^(lcol&7))*16 is
  // independent of the fragment index, so each read = base + imm.
  u32 lbase = (u32)(uintptr_t)ldsc;
  u32 comm = (u32)lcol * 128u;
  u32 aoff[2][2], boff[2][2];
  #pragma unroll
  for (int db2 = 0; db2 < 2; ++db2)
    #pragma unroll
    for (int ks2 = 0; ks2 < 2; ++ks2) {
      u32 term = ((u32)((ks2 * 4 + lrow) ^ (lcol & 7))) << 4;
      aoff[db2][ks2] = lbase + (u32)(db2 * 4 + wm) * 16384u + comm + term;
      boff[db2][ks2] = lbase + (u32)(db2 * 4 + 2 + (wn >> 1)) * 16384u +
                       (u32)(wn & 1) * 8192u + comm + term;
    }

  // stage one half-tile (piece pc: 0=A0,1=A1,2=B0,3=B1) of K-tile t, dbuf db.
  // linear LDS dest + inverse-swizzled global source column (involution).
  auto STAGE1 = [&](int db, int t, int pc) {
    int M = pc >> 1, h = pc & 1;
    int k0 = t * BK;
    const bf16* gsrc = M ? gB : gA;
    #pragma unroll
    for (int q2 = 0; q2 < 2; ++q2) {
      int ch = q2 * 512 + tid;           // 16-B chunk within 16KB piece
      int r = ch >> 3, s = ch & 7;
      int ldofs = (db * 4 + pc) * 16384 + ch * 16;
      const bf16* g = gsrc + (size_t)(h * 128 + r) * DD + k0 + ((s ^ (r & 7)) << 3);
      __builtin_amdgcn_global_load_lds(
          (const __attribute__((address_space(1))) void*)g,
          (__attribute__((address_space(3))) void*)(ldsc + ldofs), 16, 0, 0);
    }
  };

  bf16x8 a[8], b[2];
#define MMH(m) do { \
    acc[m][0] = __builtin_amdgcn_mfma_f32_16x16x32_bf16(a[m], b[0], acc[m][0], 0, 0, 0); \
    acc[m][1] = __builtin_amdgcn_mfma_f32_16x16x32_bf16(a[m], b[1], acc[m][1], 0, 0, 0); \
  } while (0)
#define MML(m) do { \
    acc[m][2] = __builtin_amdgcn_mfma_f32_16x16x32_bf16(a[m], b[0], acc[m][2], 0, 0, 0); \
    acc[m][3] = __builtin_amdgcn_mfma_f32_16x16x32_bf16(a[m], b[1], acc[m][3], 0, 0, 0); \
  } while (0)

  // heavy phase (nh==0): 10 ordered reads, staggered waits, 16 MFMA
#define PH_HEAVY(PD, KS, STT, STPC) do { \
    DSR(b[0], boff[PD][KS], "0");     DSR(b[1], boff[PD][KS], "2048"); \
    DSR(a[0], aoff[PD][KS], "0");     DSR(a[1], aoff[PD][KS], "2048"); \
    DSR(a[2], aoff[PD][KS], "4096");  DSR(a[3], aoff[PD][KS], "6144"); \
    DSR(a[4], aoff[PD][KS], "8192");  DSR(a[5], aoff[PD][KS], "10240"); \
    DSR(a[6], aoff[PD][KS], "12288"); DSR(a[7], aoff[PD][KS], "14336"); \
    if ((STT) < KT) STAGE1((STT) & 1, (STT), (STPC)); \
    __builtin_amdgcn_s_setprio(1); \
    WAITL("7"); SB0; MMH(0); \
    WAITL("6"); SB0; MMH(1); \
    WAITL("5"); SB0; MMH(2); \
    WAITL("4"); SB0; MMH(3); \
    WAITL("3"); SB0; MMH(4); \
    WAITL("2"); SB0; MMH(5); \
    WAITL("1"); SB0; MMH(6); \
    WAITL("0"); SB0; MMH(7); \
    __builtin_amdgcn_s_setprio(0); \
    __builtin_amdgcn_s_barrier(); \
  } while (0)

  // light phase (nh==1): 2 reads (a[] reused), 16 MFMA; optional vmcnt after MFMA
#define PH_LIGHT(PD, KS, STT, STPC, VMC) do { \
    DSR(b[0], boff[PD][KS], "4096");  DSR(b[1], boff[PD][KS], "6144"); \
    if ((STT) < KT) STAGE1((STT) & 1, (STT), (STPC)); \
    __builtin_amdgcn_s_setprio(1); \
    WAITL("0"); SB0; \
    MML(0); MML(1); MML(2); MML(3); MML(4); MML(5); MML(6); MML(7); \
    __builtin_amdgcn_s_setprio(0); \
    VMC; \
    __builtin_amdgcn_s_barrier(); \
  } while (0)

  // ---- prologue: tile 0 (all 4 pieces) + tile 1's A0; prime the ring
  #pragma unroll
  for (int pc = 0; pc < 4; ++pc) STAGE1(0, 0, pc);
  STAGE1(1, 1, 0);
  asm volatile("s_waitcnt vmcnt(2)" ::: "memory");   // tile 0 landed
  __builtin_amdgcn_s_barrier();

  for (int it = 0; it < KT / 2; ++it) {
    int t1 = 2 * it + 1, t2 = 2 * it + 2, t3 = 2 * it + 3;
    bool last = (it == KT / 2 - 1);
    PH_HEAVY(0, 0, t1, 1);
    PH_LIGHT(0, 0, t1, 2, (void)0);
    PH_HEAVY(0, 1, t1, 3);
    if (last) PH_LIGHT(0, 1, t2, 0, asm volatile("s_waitcnt vmcnt(0)" ::: "memory"));
    else      PH_LIGHT(0, 1, t2, 0, asm volatile("s_waitcnt vmcnt(2)" ::: "memory"));
    PH_HEAVY(1, 0, t2, 1);
    PH_LIGHT(1, 0, t2, 2, (void)0);
    PH_HEAVY(1, 1, t2, 3);
    if (last) PH_LIGHT(1, 1, t3, 0, asm volatile("s_waitcnt vmcnt(0)" ::: "memory"));
    else      PH_LIGHT(1, 1, t3, 0, asm volatile("s_waitcnt vmcnt(2)" ::: "memory"));
  }

  // ---- epilogue: bidirectional argmax to per-tile partials, no atomics ----
  __syncthreads();                  // full drain; LDS now reusable
  u64* rowLds = (u64*)ldsc;           // [4 wn][256 rows]  8KB
  u64* colLds = (u64*)(ldsc + 8192);  // [2 wm][256 cols]  4KB

  // row best: per target row, over this wave's 64 source cols
  #pragma unroll
  for (int m = 0; m < 8; ++m) {
    #pragma unroll
    for (int j = 0; j < 4; ++j) {
      u64 best = 0ull;
      #pragma unroll
      for (int n = 0; n < 4; ++n)
        best = umax(best, packSI(acc[m][n][j], (u32)(tileC + wn * 64 + n * 16 + lcol)));
      #pragma unroll
      for (int s = 1; s < 16; s <<= 1)
        best = umax(best, (u64)__shfl_xor(best, s, 64));
      if (lcol == 0)
        rowLds[wn * 256 + wm * 128 + m * 16 + lrow * 4 + j] = best;
    }
  }
  // col best: per source col, over this wave's 128 target rows
  #pragma unroll
  for (int n = 0; n < 4; ++n) {
    u64 best = 0ull;
    #pragma unroll
    for (int m = 0; m < 8; ++m)
      #pragma unroll
      for (int j = 0; j < 4; ++j)
        best = umax(best, packSI(acc[m][n][j], (u32)(tileR + wm * 128 + m * 16 + lrow * 4 + j)));
    #pragma unroll
    for (int s = 16; s < 64; s <<= 1)
      best = umax(best, (u64)__shfl_xor(best, s, 64));
    if (lrow == 0)
      colLds[wm * 256 + wn * 64 + n * 16 + lcol] = best;
  }
  __syncthreads();
  if (tid < 256) {
    u64 b2 = rowLds[tid];
    b2 = umax(b2, rowLds[256 + tid]);
    b2 = umax(b2, rowLds[512 + tid]);
    b2 = umax(b2, rowLds[768 + tid]);
    rowPart[(size_t)ct * NPAD2 + tileR + tid] = b2;
  } else {
    int c = tid - 256;
    u64 b2 = umax(colLds[c], colLds[256 + c]);
    colPart[(size_t)rt * NPAD2 + tileC + c] = b2;
  }
#undef PH_HEAVY
#undef PH_LIGHT
#undef MMH
#undef MML
}

// per-n max over 36 tile-partials + analytic loss contributions -> per-block sums
__global__ __launch_bounds__(256) void k_redloss(const u64* __restrict__ rowPart,
                                                 const u64* __restrict__ colPart,
                                                 const float* __restrict__ sq_s,
                                                 const float* __restrict__ sq_t,
                                                 float* __restrict__ part) {
  __shared__ float r0[256], r1[256];
  int t = threadIdx.x;
  int n = blockIdx.x * 256 + t;   // grid 36 -> 9216
  float lt = 0.f, ls = 0.f;
  u64 r = 0ull, c = 0ull;
  for (int i = 0; i < NT2; ++i) {
    u64 x = rowPart[(size_t)i * NPAD2 + n]; if (x > r) r = x;
    u64 y = colPart[(size_t)i * NPAD2 + n]; if (y > c) c = y;
  }
  if (n < NP) {
    {
      u32 key = (u32)(r >> 32);
      u32 bb = (key & 0x80000000u) ? (key ^ 0x80000000u) : ~key;
      float sc = __uint_as_float(bb);
      u32 m = ~((u32)r);
      float a = sq_t[n], cc = sq_s[m];
      lt = a + cc - 2.f * sc * (sqrtf(a) + FEPS) * (sqrtf(cc) + FEPS);
    }
    {
      u32 key = (u32)(c >> 32);
      u32 bb = (key & 0x80000000u) ? (key ^ 0x80000000u) : ~key;
      float sc = __uint_as_float(bb);
      u32 m = ~((u32)c);
      float a = sq_s[n], cc = sq_t[m];
      ls = a + cc - 2.f * sc * (sqrtf(a) + FEPS) * (sqrtf(cc) + FEPS);
    }
  }
  r0[t] = lt; r1[t] = ls;
  __syncthreads();
  for (int s = 128; s > 0; s >>= 1) {
    if (t < s) { r0[t] += r0[t + s]; r1[t] += r1[t + s]; }
    __syncthreads();
  }
  if (t == 0) { part[blockIdx.x * 2] = r0[0]; part[blockIdx.x * 2 + 1] = r1[0]; }
}

// deterministic final sum of the 36 per-block partials
__global__ __launch_bounds__(64) void k_fin(const float* __restrict__ part,
                                            float* __restrict__ out) {
  int l = threadIdx.x;
  float lt = (l < NT2) ? part[l * 2] : 0.f;
  float ls = (l < NT2) ? part[l * 2 + 1] : 0.f;
  #pragma unroll
  for (int s = 1; s < 64; s <<= 1) {
    lt += __shfl_xor(lt, s, 64);
    ls += __shfl_xor(ls, s, 64);
  }
  if (l == 0) {
    const float scale = 0.5f / ((float)NP * (float)DD);
    out[0] = lt * scale;   // loss_target
    out[1] = ls * scale;   // loss_source
  }
}

extern "C" void kernel_launch(void* const* d_in, const int* in_sizes, int n_in,
                              void* d_out, int out_size, void* d_ws, size_t ws_size,
                              hipStream_t stream) {
  const float* src = (const float*)d_in[0];
  const float* tgt = (const float*)d_in[1];
  float* out = (float*)d_out;
  char* ws = (char*)d_ws;
  size_t o = 0;
  bf16* Sn = (bf16*)(ws + o); o += (size_t)NPAD2 * DD * 2;
  bf16* Tn = (bf16*)(ws + o); o += (size_t)NPAD2 * DD * 2;
  float* sq_s = (float*)(ws + o); o += (size_t)NPAD2 * 4;
  float* sq_t = (float*)(ws + o); o += (size_t)NPAD2 * 4;
  float* q_s = (float*)(ws + o); o += (size_t)HH * WW * 4;
  float* q_t = (float*)(ws + o); o += (size_t)HH * WW * 4;
  u64* rowPart = (u64*)(ws + o); o += (size_t)NT2 * NPAD2 * 8;
  u64* colPart = (u64*)(ws + o); o += (size_t)NT2 * NPAD2 * 8;
  float* part = (float*)(ws + o); o += 1024;
  if (ws_size < o) return;  // ~43 MiB needed

  k_q<<<dim3(36, 2), 256, 0, stream>>>(src, tgt, q_s, q_t, Sn, Tn);
  k_sq<<<36, 256, 0, stream>>>(q_s, q_t, sq_s, sq_t);
  k_norm<<<dim3(16, PH, 2), 128, 0, stream>>>(src, tgt, sq_s, sq_t, Sn, Tn);
  k_gemm<<<NBLK2, 512, 0, stream>>>(Tn, Sn, rowPart, colPart);
  k_redloss<<<36, 256, 0, stream>>>(rowPart, colPart, sq_s, sq_t, part);
  k_fin<<<1, 64, 0, stream>>>(part, out);
}